// Round 6
// baseline (115.294 us; speedup 1.0000x reference)
//
#include <hip/hip_runtime.h>

typedef __attribute__((ext_vector_type(8))) _Float16 f16x8;
typedef __attribute__((ext_vector_type(4))) _Float16 f16x4;
typedef __attribute__((ext_vector_type(4))) float   f32x4;

#define BATCH 16384
#define NFEAT 512
#define NCLS  1000
#define NLEAF 256
#define NINT  255
#define NPAD  1024
#define LDP   72    // staging LDS row stride (f16): 144B -> optimal 8-slot spread for b128
#define MUP   264   // mu LDS row stride (f16): 528B, 528/16=33 odd -> optimal spread
#define PSTR  257   // P LDS row stride (f32): breaks the 4-way bank conflict on P writes
#define CSTR  516   // C-assembly row stride (f32)

// ---- convert gate_w (255x512) -> f16 padded to 256x512 (row 255 = 0) ----
__global__ __launch_bounds__(256) void cvt_gw(const float4* __restrict__ in,
                                              f16x4* __restrict__ out) {
  int i = blockIdx.x * 256 + threadIdx.x;   // quad index, 32768 total
  int row = i >> 7;
  f16x4 o;
  if (row < NINT) {
    float4 v = in[i];
    o[0] = (_Float16)v.x; o[1] = (_Float16)v.y;
    o[2] = (_Float16)v.z; o[3] = (_Float16)v.w;
  } else {
    o[0] = o[1] = o[2] = o[3] = (_Float16)0.f;
  }
  out[i] = o;
}

// ---- softmax rows of leaf_logits (256x1000) -> distT[c][l] f16, rows 1000..1023 zeroed ----
__global__ __launch_bounds__(256) void softmax_t(const float* __restrict__ L,
                                                 _Float16* __restrict__ distT) {
  __shared__ float red[4];
  const int l = blockIdx.x, t = threadIdx.x;
  const int wave = t >> 6, lane = t & 63;
  float v[4];
  if (t < 250) {
    float4 f = *(const float4*)&L[(size_t)l * NCLS + t * 4];
    v[0] = f.x; v[1] = f.y; v[2] = f.z; v[3] = f.w;
  } else {
    v[0] = v[1] = v[2] = v[3] = -1e30f;
  }
  float mx = fmaxf(fmaxf(v[0], v[1]), fmaxf(v[2], v[3]));
#pragma unroll
  for (int s = 32; s; s >>= 1) mx = fmaxf(mx, __shfl_xor(mx, s));
  if (lane == 0) red[wave] = mx;
  __syncthreads();
  mx = fmaxf(fmaxf(red[0], red[1]), fmaxf(red[2], red[3]));
  __syncthreads();
  float e[4], sum = 0.f;
#pragma unroll
  for (int i = 0; i < 4; ++i) { e[i] = __expf(v[i] - mx); sum += e[i]; }
  if (t >= 250) { e[0] = e[1] = e[2] = e[3] = 0.f; sum = 0.f; }
#pragma unroll
  for (int s = 32; s; s >>= 1) sum += __shfl_xor(sum, s);
  if (lane == 0) red[wave] = sum;
  __syncthreads();
  sum = red[0] + red[1] + red[2] + red[3];
  float inv = 1.f / sum;
  if (t < 250) {
#pragma unroll
    for (int i = 0; i < 4; ++i)
      distT[(size_t)(t * 4 + i) * NLEAF + l] = (_Float16)(e[i] * inv);
  }
  if (t < NPAD - NCLS) distT[(size_t)(NCLS + t) * NLEAF + l] = (_Float16)0.f;
}

// ---- fused: gemm1 + sigmoid + tree + gemm2 with row-streaming epilogue ----
// BM=32 rows/block, 512 blocks, 512 threads (8 waves), 2 blocks/CU.
__global__ __launch_bounds__(512, 4)
void fused(const float* __restrict__ x, const _Float16* __restrict__ gwh,
           const float* __restrict__ gb, const _Float16* __restrict__ distT,
           float* __restrict__ out) {
  __shared__ union {
    struct { _Float16 A[32 * LDP]; _Float16 B[256 * LDP]; } s;  // 41,472 B
    float P[32 * PSTR];                                         // 32,896 B
    float C[16 * CSTR];                                         // 33,024 B
  } sm;
  __shared__ _Float16 sMu[32 * MUP];                            // 16,896 B
  // union 41,472 + 16,896 = 58,368 B -> 2 blocks/CU

  const int tid  = threadIdx.x;
  const int wave = tid >> 6, lane = tid & 63;
  const int ln15 = lane & 15, lhi = lane >> 4;
  const int wr = wave >> 2, wc = wave & 3;      // 2x4 waves: 16 rows x 64 cols
  const int r0 = blockIdx.x * 32;

  // bias preload (overlaps first staging latency)
  float bias_[4];
#pragma unroll
  for (int n = 0; n < 4; ++n) {
    int col = wc * 64 + n * 16 + ln15;
    bias_[n] = (col < NINT) ? gb[col] : 0.f;
  }

  // ---------------- phase 1: logits = x @ gwh^T ----------------
  f32x4 acc1[4] = {};
  const int arow = tid >> 4, acol = (tid & 15) * 4;  // A: 1 float4/thread
  const int brow = tid >> 3, bcol = (tid & 7) * 8;   // B: 4 uint4/thread

  float4 pa;
  uint4  pb[4];

#define P1_LOAD(k0)                                                              \
  {                                                                              \
    pa = *(const float4*)&x[(size_t)(r0 + arow) * NFEAT + (k0) + acol];          \
    _Pragma("unroll")                                                            \
    for (int i = 0; i < 4; ++i)                                                  \
      pb[i] = *(const uint4*)&gwh[(size_t)(i * 64 + brow) * NFEAT + (k0) + bcol];\
  }
#define P1_WRITE()                                                               \
  {                                                                              \
    f16x4 h;                                                                     \
    h[0] = (_Float16)pa.x; h[1] = (_Float16)pa.y;                                \
    h[2] = (_Float16)pa.z; h[3] = (_Float16)pa.w;                                \
    *(f16x4*)&sm.s.A[arow * LDP + acol] = h;                                     \
    _Pragma("unroll")                                                            \
    for (int i = 0; i < 4; ++i)                                                  \
      *(uint4*)&sm.s.B[(i * 64 + brow) * LDP + bcol] = pb[i];                    \
  }

  P1_LOAD(0);
  for (int k = 0; k < NFEAT / 64; ++k) {
    P1_WRITE();
    __syncthreads();
    if (k < NFEAT / 64 - 1) P1_LOAD((k + 1) * 64);   // next loads fly over MFMA
#pragma unroll
    for (int kk = 0; kk < 2; ++kk) {
      f16x8 a, b[4];
      a = *(const f16x8*)&sm.s.A[(wr * 16 + ln15) * LDP + kk * 32 + lhi * 8];
#pragma unroll
      for (int n = 0; n < 4; ++n)
        b[n] = *(const f16x8*)&sm.s.B[(wc * 64 + n * 16 + ln15) * LDP + kk * 32 + lhi * 8];
#pragma unroll
      for (int n = 0; n < 4; ++n)
        acc1[n] = __builtin_amdgcn_mfma_f32_16x16x32_f16(a, b[n], acc1[n], 0, 0, 0);
    }
    __syncthreads();
  }

  // ---------------- phase 2a: sigmoid -> P (LDS, stride 257) ----------------
#pragma unroll
  for (int n = 0; n < 4; ++n) {
    int col = wc * 64 + n * 16 + ln15;
#pragma unroll
    for (int j = 0; j < 4; ++j) {
      int rl = wr * 16 + lhi * 4 + j;
      float v = acc1[n][j] + bias_[n];
      sm.P[rl * PSTR + col] = 1.f / (1.f + __expf(-v));
    }
  }
  __syncthreads();

  // ---------------- phase 2b: tree product -> sMu ----------------
  const int lf = lane * 4;
#pragma unroll
  for (int rr = 0; rr < 4; ++rr) {
    int row = wave * 4 + rr;
    const float* p = &sm.P[row * PSTR];
    float pre = 1.f;
#pragma unroll
    for (int d = 0; d < 6; ++d) {
      int node = (1 << d) - 1 + (lf >> (8 - d));
      int bit  = (lf >> (7 - d)) & 1;
      float g = p[node];
      pre *= bit ? g : (1.f - g);
    }
    float g6  = p[63 + lane];
    float g7a = p[127 + 2 * lane];
    float g7b = p[128 + 2 * lane];
    f16x4 o;
    o[0] = (_Float16)(pre * (1.f - g6) * (1.f - g7a));
    o[1] = (_Float16)(pre * (1.f - g6) * g7a);
    o[2] = (_Float16)(pre * g6 * (1.f - g7b));
    o[3] = (_Float16)(pre * g6 * g7b);
    *(f16x4*)&sMu[row * MUP + lf] = o;
  }
  __syncthreads();

  // ---------------- phase 3: out = mu @ distT^T, row-streaming epilogue ----------------
  const int wr2 = wave >> 2, wc2 = wave & 3;   // rows wr2*16..+16, col-block wc2*128
  f16x8 aa[8];
#pragma unroll
  for (int kk = 0; kk < 8; ++kk)
    aa[kk] = *(const f16x8*)&sMu[(wr2 * 16 + ln15) * MUP + kk * 32 + lhi * 8];

  for (int half = 0; half < 2; ++half) {
    f32x4 acc[8] = {};   // col = half*512 + wc2*128 + n*16 + ln15
#pragma unroll
    for (int n = 0; n < 8; ++n) {
      const int cc = half * 512 + wc2 * 128 + n * 16 + ln15;
      f16x8 bb[8];
#pragma unroll
      for (int kk = 0; kk < 8; ++kk)
        bb[kk] = *(const f16x8*)&distT[(size_t)cc * NLEAF + kk * 32 + lhi * 8];
#pragma unroll
      for (int kk = 0; kk < 8; ++kk)
        acc[n] = __builtin_amdgcn_mfma_f32_16x16x32_f16(aa[kk], bb[kk], acc[n], 0, 0, 0);
    }
    const int ncols = (half == 0) ? 512 : (NCLS - 512);
    // two 16-row chunks, assembled in LDS, streamed as full contiguous rows
#pragma unroll
    for (int ch = 0; ch < 2; ++ch) {
      __syncthreads();   // previous chunk's reads (or P-phase) complete
      if (wr2 == ch) {
#pragma unroll
        for (int n = 0; n < 8; ++n)
#pragma unroll
          for (int j = 0; j < 4; ++j)
            sm.C[(lhi * 4 + j) * CSTR + wc2 * 128 + n * 16 + ln15] = acc[n][j];
      }
      __syncthreads();
      // stream 16 rows, 2 rows per wave, contiguous 2KB bursts
#pragma unroll
      for (int rr = 0; rr < 2; ++rr) {
        int lr = wave * 2 + rr;
        size_t gbase = (size_t)(r0 + ch * 16 + lr) * NCLS + half * 512;
#pragma unroll
        for (int i = 0; i < 2; ++i) {
          int q = i * 64 + lane;       // float4 index within half-row
          if (q * 4 < ncols) {
            f32x4 v = *(const f32x4*)&sm.C[lr * CSTR + q * 4];
            __builtin_nontemporal_store(v, (f32x4*)&out[gbase + q * 4]);
          }
        }
      }
    }
  }
#undef P1_LOAD
#undef P1_WRITE
}

extern "C" void kernel_launch(void* const* d_in, const int* in_sizes, int n_in,
                              void* d_out, int out_size, void* d_ws, size_t ws_size,
                              hipStream_t stream) {
  const float* x  = (const float*)d_in[0];   // 16384x512
  const float* gw = (const float*)d_in[1];   // 255x512
  const float* gb = (const float*)d_in[2];   // 255
  const float* ll = (const float*)d_in[3];   // 256x1000
  float* out = (float*)d_out;                // 16384x1000
  char* ws = (char*)d_ws;

  _Float16* gwh   = (_Float16*)(ws);            // 262,144 B
  _Float16* distT = (_Float16*)(ws + 262144);   // 524,288 B

  cvt_gw   <<<128, 256, 0, stream>>>((const float4*)gw, (f16x4*)gwh);
  softmax_t<<<256, 256, 0, stream>>>(ll, distT);
  fused    <<<BATCH / 32, 512, 0, stream>>>(x, gwh, gb, distT, out);
}